// Round 13
// baseline (30.989 us; speedup 1.0000x reference)
//
#include <hip/hip_runtime.h>
#include <math.h>

#define BB 64
#define HH 512
#define IN_DIM 256
#define OUT_DIM 256

typedef float f4 __attribute__((ext_vector_type(4)));
typedef float f2 __attribute__((ext_vector_type(2)));

__device__ __forceinline__ float fast_tanh(float x) {
    const float ax = fabsf(x);
    const float e  = __expf(2.f * ax);
    const float t  = 1.f - 2.f / (e + 1.f);
    return copysignf(t, x);
}

__device__ __forceinline__ f4 clamp1(f4 v) {
    return __builtin_elementwise_min(__builtin_elementwise_max(v, (f4)(-1.f)), (f4)(1.f));
}

// One wave handles TWO rows (b, i0), (b, i0+1) of hebb.
// i-slow / b-fast logical order + bijective XCD swizzle (grid 4096 = 8*512):
// XCD k executes logical blocks [512k, 512k+512) = 64 consecutive i-rows of
// w/alpha (256 KB, L2-resident per XCD) over all 64 batches.
// __launch_bounds__(256, 8): min 8 waves/SIMD -> 32 waves/CU resident,
// 16 light block-generations per CU for a smooth load/store pipeline.
__global__ __launch_bounds__(256, 8) void fused_row_kernel(
    const float* __restrict__ inputs, const float* __restrict__ prev,
    const float* __restrict__ hebb,   const float* __restrict__ w,
    const float* __restrict__ alpha,  const float* __restrict__ eta,
    const float* __restrict__ Wi,     const float* __restrict__ bi,
    float* __restrict__ hidden, float* __restrict__ hebb_new)
{
    const int h   = blockIdx.x;
    const int cpx = gridDim.x >> 3;            // 512
    const int L   = (h & 7) * cpx + (h >> 3);  // bijective XCD swizzle

    const int wid2 = (L * 256 + (int)threadIdx.x) >> 6;  // [0, H/2*B)
    const int lane = threadIdx.x & 63;
    const int b  = wid2 & (BB - 1);      // batch fast
    const int i0 = (wid2 >> 6) * 2;      // row pair slow
    const int i1 = i0 + 1;

    const size_t rowA = ((size_t)b * HH + i0) * HH;
    const size_t rowB = rowA + HH;

    const int j0 = lane * 4;
    const int j1 = j0 + 256;

    const float* prow = prev + (size_t)b * HH;
    const f4 p0 = *(const f4*)(prow + j0);
    const f4 p1 = *(const f4*)(prow + j1);

    const f4 hA0 = *(const f4*)(hebb + rowA + j0);
    const f4 hA1 = *(const f4*)(hebb + rowA + j1);
    const f4 hB0 = *(const f4*)(hebb + rowB + j0);
    const f4 hB1 = *(const f4*)(hebb + rowB + j1);

    const f4 wA0 = *(const f4*)(w + (size_t)i0 * HH + j0);
    const f4 wA1 = *(const f4*)(w + (size_t)i0 * HH + j1);
    const f4 wB0 = *(const f4*)(w + (size_t)i1 * HH + j0);
    const f4 wB1 = *(const f4*)(w + (size_t)i1 * HH + j1);

    const f4 aA0 = *(const f4*)(alpha + (size_t)i0 * HH + j0);
    const f4 aA1 = *(const f4*)(alpha + (size_t)i0 * HH + j1);
    const f4 aB0 = *(const f4*)(alpha + (size_t)i1 * HH + j0);
    const f4 aB1 = *(const f4*)(alpha + (size_t)i1 * HH + j1);

    f4 vA = (wA0 + aA0 * hA0) * p0 + (wA1 + aA1 * hA1) * p1;
    f4 vB = (wB0 + aB0 * hB0) * p0 + (wB1 + aB1 * hB1) * p1;

    const f4 xv  = *(const f4*)(inputs + (size_t)b * IN_DIM + j0);
    const f4 wiA = *(const f4*)(Wi + (size_t)i0 * IN_DIM + j0);
    const f4 wiB = *(const f4*)(Wi + (size_t)i1 * IN_DIM + j0);
    vA += wiA * xv;
    vB += wiB * xv;

    float accA = vA.x + vA.y + vA.z + vA.w;
    float accB = vB.x + vB.y + vB.z + vB.w;

    #pragma unroll
    for (int d = 32; d > 0; d >>= 1) {
        accA += __shfl_xor(accA, d, 64);
        accB += __shfl_xor(accB, d, 64);
    }

    const float hvA = fast_tanh(accA + bi[i0]);
    const float hvB = fast_tanh(accB + bi[i1]);
    if (lane == 0) {
        f2 hv; hv.x = hvA; hv.y = hvB;
        *(f2*)(hidden + (size_t)b * HH + i0) = hv;   // i0 even -> 8B aligned
    }

    const float et = eta[0];
    const float eA = et * hvA;
    const float eB = et * hvB;

    *(f4*)(hebb_new + rowA + j0) = clamp1(hA0 + eA * p0);
    *(f4*)(hebb_new + rowA + j1) = clamp1(hA1 + eA * p1);
    *(f4*)(hebb_new + rowB + j0) = clamp1(hB0 + eB * p0);
    *(f4*)(hebb_new + rowB + j1) = clamp1(hB1 + eB * p1);
}

// One wave per output element: o in [0,256) -> a_out[b,o]; o==256 -> v_out[b].
__global__ __launch_bounds__(256) void out_proj_kernel(
    const float* __restrict__ hidden, const float* __restrict__ Wo,
    const float* __restrict__ bo,     const float* __restrict__ Wv,
    const float* __restrict__ bv,
    float* __restrict__ a_out, float* __restrict__ v_out)
{
    const int wid  = (blockIdx.x * 256 + threadIdx.x) >> 6;  // [0, 64*257)
    const int lane = threadIdx.x & 63;
    const int b = wid / 257;
    const int o = wid - b * 257;

    const int j0 = lane * 4;
    const int j1 = j0 + 256;

    const float* hrow = hidden + (size_t)b * HH;
    const f4 h0 = *(const f4*)(hrow + j0);
    const f4 h1 = *(const f4*)(hrow + j1);

    const float* wrow = (o < OUT_DIM) ? (Wo + (size_t)o * HH) : Wv;
    const f4 w0 = *(const f4*)(wrow + j0);
    const f4 w1 = *(const f4*)(wrow + j1);

    const f4 pv = h0 * w0 + h1 * w1;
    float acc = pv.x + pv.y + pv.z + pv.w;

    #pragma unroll
    for (int d = 32; d > 0; d >>= 1) acc += __shfl_xor(acc, d, 64);

    if (lane == 0) {
        if (o < OUT_DIM) a_out[(size_t)b * OUT_DIM + o] = acc + bo[o];
        else             v_out[b] = acc + bv[0];
    }
}

extern "C" void kernel_launch(void* const* d_in, const int* in_sizes, int n_in,
                              void* d_out, int out_size, void* d_ws, size_t ws_size,
                              hipStream_t stream) {
    const float* inputs = (const float*)d_in[0];
    const float* prev   = (const float*)d_in[1];
    const float* hebb   = (const float*)d_in[2];
    const float* w      = (const float*)d_in[3];
    const float* alpha  = (const float*)d_in[4];
    const float* eta    = (const float*)d_in[5];
    const float* Wi     = (const float*)d_in[6];
    const float* bi     = (const float*)d_in[7];
    const float* Wo     = (const float*)d_in[8];
    const float* bo     = (const float*)d_in[9];
    const float* Wv     = (const float*)d_in[10];
    const float* bv     = (const float*)d_in[11];

    float* out      = (float*)d_out;
    float* a_out    = out;                       // [B, OUT]
    float* v_out    = a_out + BB * OUT_DIM;      // [B, 1]
    float* hidden   = v_out + BB;                // [B, H]
    float* hebb_new = hidden + BB * HH;          // [B, H, H]

    // H/2 * B = 16384 waves, 4 per block -> 4096 blocks (multiple of 8)
    fused_row_kernel<<<dim3(HH / 2 * BB / 4), dim3(256), 0, stream>>>(
        inputs, prev, hebb, w, alpha, eta, Wi, bi, hidden, hebb_new);

    out_proj_kernel<<<dim3((BB * 257 + 3) / 4), dim3(256), 0, stream>>>(
        hidden, Wo, bo, Wv, bv, a_out, v_out);
}